// Round 20
// baseline (864.552 us; speedup 1.0000x reference)
//
#include <hip/hip_runtime.h>
#include <math.h>

#define BATCH  128
#define CIN    256
#define HWSZ   1024
#define NATT   64
#define TRI    2080
#define PLANES 256

typedef __attribute__((ext_vector_type(8))) short short8v;
typedef __attribute__((ext_vector_type(4))) float f32x4;

// raw barrier: LDS-visibility drain only, NO vmcnt drain (prefetch stays in flight)
#define BAR() { asm volatile("s_waitcnt lgkmcnt(0)" ::: "memory"); __builtin_amdgcn_s_barrier(); }

// ---------------- workspace layout (float slots) ----------------
static const size_t WHI_OFF   = 0;         // uint [64][128]       8192
static const size_t WLO_OFF   = 8192;      // uint [64][128]       8192
static const size_t GATE_OFF  = 16384;     // [128][256]           32768
static const size_t PSUM_OFF  = 49152;     // [1024][64]           65536
static const size_t PGRAM_OFF = 114688;    // [1024][64][64]       4194304
static const size_t VEC_OFF   = 4308992;   // [128][2080]          266240

// ---------------- helpers ----------------
__device__ __forceinline__ unsigned int bf16rne(float f){
  unsigned int u = __float_as_uint(f);
  return (u + 0x7fffu + ((u>>16)&1u)) >> 16;
}
__device__ __forceinline__ unsigned int pk2(float a, float b){
  return bf16rne(a) | (bf16rne(b)<<16);
}
__device__ __forceinline__ unsigned int pack_hl(float v){
  unsigned int b  = __float_as_uint(v);
  unsigned int hb = b >> 16;
  float hif = __uint_as_float(hb << 16);
  float lo  = v - hif;
  unsigned int lb = __float_as_uint(lo) >> 16;
  return hb | (lb << 16);
}
union U4S8 { uint4 u; short8v s; };
__device__ __forceinline__ short8v bc8(uint4 v){ U4S8 x; x.u = v; return x.s; }

__device__ __forceinline__ void unpack8p(const unsigned int* w, short8v& h, short8v& l){
  union { unsigned int u[4]; short8v s; } H, L;
#pragma unroll
  for (int i=0;i<4;i++){
    H.u[i] = __builtin_amdgcn_perm(w[2*i+1], w[2*i], 0x05040100u);
    L.u[i] = __builtin_amdgcn_perm(w[2*i+1], w[2*i], 0x07060302u);
  }
  h = H.s; l = L.s;
}
__device__ __forceinline__ void unpack8v(uint4 a, uint4 b, short8v& h, short8v& l){
  unsigned int w[8] = {a.x,a.y,a.z,a.w,b.x,b.y,b.z,b.w};
  unpack8p(w, h, l);
}

// ---------------- kernel 0: pack conv_w to bf16 hi/lo PAIR arrays ----------------
__global__ void k_pack_w2(const float* __restrict__ w,
                          unsigned int* __restrict__ whi, unsigned int* __restrict__ wlo){
  int idx = blockIdx.x*256 + threadIdx.x;
  if (idx < 64*128){
    float w0 = w[2*idx], w1 = w[2*idx+1];
    unsigned int h0 = __float_as_uint(w0)>>16, h1 = __float_as_uint(w1)>>16;
    float l0f = w0 - __uint_as_float(h0<<16);
    float l1f = w1 - __uint_as_float(h1<<16);
    whi[idx] = h0 | (h1<<16);
    wlo[idx] = (__float_as_uint(l0f)>>16) | ((__float_as_uint(l1f)>>16)<<16);
  }
}

// ---------------- kernel 1: conv+BN+ReLU+gram (R16 best) — 11x IN-KERNEL REPEAT
// MEASUREMENT ROUND: body repeated 11x (idempotent; acc re-zeroed per rep,
// barriers at rep boundaries protect the xs/yt alias). Makes the conv dispatch
// top the PMC table (full counter signature at last) and discriminates:
// memory-path-bound -> reps 2-11 run from L3 (total ~400-450us);
// internal-structure-bound -> reps unchanged (total ~735us).
__global__ __launch_bounds__(512, 6) void k_conv_gram(
    const float* __restrict__ x,
    const unsigned int* __restrict__ whi, const unsigned int* __restrict__ wlo,
    const float* __restrict__ gam, const float* __restrict__ bet,
    const float* __restrict__ mu,  const float* __restrict__ var,
    float* __restrict__ pgram, float* __restrict__ psum){
  __shared__ __align__(16) unsigned char pool[2*128*20*4];   // 20480 B
  __shared__ float scl[64], shf[64];
  __shared__ float psl[2][64];
  unsigned int (*xsb[2])[20];
  xsb[0] = (unsigned int (*)[20])pool;
  xsb[1] = xsb[0] + 128;
  unsigned int (*yt)[68]  = (unsigned int (*)[68])pool;      // alias (17408 B)
  // XCD swizzle: all 8 chunks of batch b on one XCD
  int i_hw  = blockIdx.x;
  int xcd   = i_hw & 7;
  int slot  = i_hw >> 3;
  int b     = xcd + ((slot >> 3) << 3);
  int chunk = slot & 7;
  int pslot = b*8 + chunk;
  int tid = threadIdx.x;
  int l = tid & 63, w = tid >> 6;
  int i16 = l & 15, q = l >> 4;
  int o0 = (w & 3) * 16, phalf = (w >> 2) * 64;
  if (tid < 64){
    float sc = gam[tid]*rsqrtf(var[tid]+1e-5f);
    scl[tid] = sc; shf[tid] = bet[tid] - mu[tid]*sc;
  }
  int cS = tid >> 5;          // 0..15 : c-pair
  int pS = tid & 31;          // pixel base
  const float* xc = x + ((size_t)b*CIN + 2*cS)*HWSZ + chunk*128 + pS;
  const unsigned int* whiR = whi + (o0+i16)*128 + q*4;
  const unsigned int* wloR = wlo + (o0+i16)*128 + q*4;

#define LOADSET(R, S) { const float* xn = xc + (size_t)(S)*32*HWSZ; \
  _Pragma("unroll") for (int j=0;j<4;j++){ va[R][j] = xn[32*j]; vb[R][j] = xn[HWSZ + 32*j]; } }
#define WRITESET(R, BUF) { \
  _Pragma("unroll") for (int j=0;j<4;j++) xsb[BUF][pS+32*j][cS] = pk2(va[R][j], vb[R][j]); }
#define WLOAD(P, S) { wh[P] = *(const uint4*)(whiR + (S)*16); \
                      wl[P] = *(const uint4*)(wloR + (S)*16); }

  __syncthreads();
#pragma unroll 1
  for (int rep = 0; rep < 11; ++rep){
    f32x4 acc[4];
#pragma unroll
    for (int t=0;t<4;t++) acc[t] = (f32x4){0.f,0.f,0.f,0.f};
    float va[3][4], vb[3][4];
    uint4 wh[2], wl[2];

    // prologue: x tiles 0,1,2 in regs; w steps 0,1 in slots; buf0 <- x0
    LOADSET(0, 0)
    LOADSET(1, 1)
    LOADSET(2, 2)
    WLOAD(0, 0)
    WLOAD(1, 1)
    WRITESET(0, 0)

#pragma unroll
    for (int cc=0; cc<8; ++cc){
      BAR();                                        // lgkm-only
      uint4 ahi = wh[cc & 1];                       // w(cc) — read BEFORE slot reuse
      uint4 alo = wl[cc & 1];
      if (cc < 5) LOADSET(cc % 3, cc + 3)           // x for step cc+3
      if (cc < 6) WLOAD(cc & 1, cc + 2)             // w for step cc+2 into freed slot
#pragma unroll
      for (int t=0;t<4;t++){
        uint4 bv = *(const uint4*)&xsb[cc & 1][phalf + t*16 + i16][q*4];
        acc[t] = __builtin_amdgcn_mfma_f32_16x16x32_bf16(bc8(ahi), bc8(bv), acc[t],0,0,0);
        acc[t] = __builtin_amdgcn_mfma_f32_16x16x32_bf16(bc8(alo), bc8(bv), acc[t],0,0,0);
      }
      if (cc < 7) WRITESET((cc + 1) % 3, (cc + 1) & 1)   // x(cc+1) -> other buf
    }
    __syncthreads();   // xs dead; pool becomes yt
    // epilogue: BN + ReLU, pack pairs -> yt; row sums
    float rs[4] = {0.f,0.f,0.f,0.f};
#pragma unroll
    for (int t=0;t<4;t++){
      int p = phalf + t*16 + i16;
#pragma unroll
      for (int r=0;r<4;r++){
        int o = o0 + q*4 + r;
        float vv = fmaf(acc[t][r], scl[o], shf[o]);
        vv = vv>0.f ? vv : 0.f;
        rs[r] += vv;
        float nb = __shfl_xor(vv, 1);
        if (!(i16 & 1)) yt[o][p>>1] = pk2(vv, nb);
      }
    }
#pragma unroll
    for (int r=0;r<4;r++){
#pragma unroll
      for (int m=1;m<16;m<<=1) rs[r] += __shfl_xor(rs[r], m, 16);
    }
    if (i16 == 0){
#pragma unroll
      for (int r=0;r<4;r++) psl[w>>2][o0 + q*4 + r] = rs[r];
    }
    __syncthreads();
    if (tid < 64) psum[(size_t)pslot*64 + tid] = psl[0][tid] + psl[1][tid];
    // gram = Y Y^T over 128 px
    {
      f32x4 g0 = (f32x4){0.f,0.f,0.f,0.f}, g1 = g0;
      int ti = w >> 1, tj0 = (w & 1) * 2;
#pragma unroll
      for (int ks=0; ks<4; ks++){
        int ku = ks*16 + q*4;
        uint4 a  = *(const uint4*)&yt[ti*16      + i16][ku];
        uint4 b0 = *(const uint4*)&yt[tj0*16     + i16][ku];
        uint4 b1 = *(const uint4*)&yt[(tj0+1)*16 + i16][ku];
        g0 = __builtin_amdgcn_mfma_f32_16x16x32_bf16(bc8(a), bc8(b0), g0,0,0,0);
        g1 = __builtin_amdgcn_mfma_f32_16x16x32_bf16(bc8(a), bc8(b1), g1,0,0,0);
      }
      float* pg = pgram + (size_t)pslot*4096;
#pragma unroll
      for (int r=0;r<4;r++){
        int i = ti*16 + q*4 + r;
        pg[i*64 + tj0*16     + i16] = g0[r];
        pg[i*64 + (tj0+1)*16 + i16] = g1[r];
      }
    }
    __syncthreads();   // protect pool before next rep's WRITESET
  }
#undef LOADSET
#undef WRITESET
#undef WLOAD
}

// P = L @ R for 64x64 packed hi/lo (R symmetric: B-frags read row-wise).
__device__ __forceinline__ void wave_mm(const unsigned int (*PL)[68],
                                        const unsigned int (*PR)[68],
                                        int lane, int rp, int ch, f32x4* acc){
  f32x4 z = {0.f,0.f,0.f,0.f};
  acc[0] = z; acc[1] = z;
  int i15 = lane & 15, q = lane >> 4;
  int row = rp*16 + i15;
#pragma unroll
  for (int s=0; s<2; s++){
    int kbase = s*32 + (q<<3);
    uint4 a0 = *(const uint4*)&PL[row][kbase];
    uint4 a1 = *(const uint4*)&PL[row][kbase+4];
    short8v ah, al; unpack8v(a0,a1,ah,al);
#pragma unroll
    for (int ct=0; ct<2; ct++){
      const unsigned int* bp = &PR[ch*32 + ct*16 + i15][kbase];
      uint4 b0 = *(const uint4*)bp;
      uint4 b1 = *(const uint4*)(bp+4);
      short8v bh, bl; unpack8v(b0,b1,bh,bl);
      acc[ct] = __builtin_amdgcn_mfma_f32_16x16x32_bf16(ah, bh, acc[ct], 0,0,0);
      acc[ct] = __builtin_amdgcn_mfma_f32_16x16x32_bf16(ah, bl, acc[ct], 0,0,0);
      acc[ct] = __builtin_amdgcn_mfma_f32_16x16x32_bf16(al, bh, acc[ct], 0,0,0);
    }
  }
}

template<int MODE>  // 0: pack(v)  1: pack(0.5*(3I-v))  2: pack(3I-v)
__device__ __forceinline__ void store_packed(unsigned int (*PD)[68], const f32x4* acc,
                                             int lane, int rp, int ch){
  int i15 = lane & 15, q = lane >> 4;
#pragma unroll
  for (int ct=0; ct<2; ct++){
    int col = ch*32 + ct*16 + i15;
#pragma unroll
    for (int r=0; r<4; r++){
      int row = rp*16 + q*4 + r;
      float v = acc[ct][r];
      if (MODE==1) v = 0.5f*((row==col?3.f:0.f) - v);
      if (MODE==2) v = (row==col?3.f:0.f) - v;
      PD[row][col] = pack_hl(v);
    }
  }
}

// ---------------- kernel 2: Newton-Schulz + triuvec -> vec ----------------
__global__ __launch_bounds__(512) void k_ns(const float* __restrict__ pgram,
    const float* __restrict__ psum, float* __restrict__ vecg){
  __shared__ float Af[64][68];
  __shared__ unsigned int PA[64][68];
  __shared__ unsigned int PT[64][68];
  __shared__ unsigned int PY[64][68];
  __shared__ unsigned int PZ[64][68];
  __shared__ float meanl[64];
  __shared__ float snorm;
  int b = blockIdx.x, tid = threadIdx.x;
  int lane = tid & 63, wv = tid >> 6, rp = wv & 3, ch = wv >> 2;
  const float* pc0 = pgram + ((size_t)b*8) * (NATT*NATT);
  if (tid < 64){
    const float* ps = psum + (size_t)b*512;
    float s = 0.f;
#pragma unroll
    for (int k=0;k<8;k++) s += ps[64*k + tid];
    meanl[tid] = s * (1.f/1024.f);
  }
  __syncthreads();
  for (int e=tid; e<4096; e+=512){
    int i = e>>6, j = e&63;
    float s = 0.f;
#pragma unroll
    for (int k=0;k<8;k++) s += pc0[4096*k + e];
    Af[i][j] = s * (1.f/1024.f) - meanl[i]*meanl[j];
  }
  __syncthreads();
  if (tid < 64){
    float s = Af[tid][tid];
#pragma unroll
    for (int off=32; off; off>>=1) s += __shfl_down(s, off);
    if (tid==0) snorm = s;
  }
  __syncthreads();
  float normA = snorm;
  float inv = 1.f/normA;
  for (int e=tid; e<4096; e+=512){
    int i = e>>6, j = e&63;
    float an = Af[i][j]*inv;
    float t  = 0.5f*((i==j?3.f:0.f) - an);
    unsigned int pt = pack_hl(t);
    PA[i][j] = pack_hl(an);
    PT[i][j] = pt;
    PZ[i][j] = pt;
  }
  __syncthreads();

  f32x4 accY[2], accZ[2];
  wave_mm(PA, PT, lane, rp, ch, accY);
  store_packed<0>(PY, accY, lane, rp, ch);
  __syncthreads();

  for (int it=0; it<3; ++it){
    wave_mm(PZ, PY, lane, rp, ch, accY);
    store_packed<1>(PT, accY, lane, rp, ch);
    __syncthreads();
    wave_mm(PY, PT, lane, rp, ch, accY);
    wave_mm(PT, PZ, lane, rp, ch, accZ);
    __syncthreads();
    store_packed<0>(PY, accY, lane, rp, ch);
    store_packed<0>(PZ, accZ, lane, rp, ch);
    __syncthreads();
  }
  wave_mm(PZ, PY, lane, rp, ch, accY);
  store_packed<2>(PT, accY, lane, rp, ch);
  __syncthreads();
  wave_mm(PY, PT, lane, rp, ch, accY);
  float scl = 0.5f * sqrtf(normA);
  {
    int i15 = lane & 15, q = lane >> 4;
#pragma unroll
    for (int ct=0; ct<2; ct++){
      int col = ch*32 + ct*16 + i15;
#pragma unroll
      for (int r=0; r<4; r++){
        int row = rp*16 + q*4 + r;
        Af[row][col] = accY[ct][r]*scl;
      }
    }
  }
  __syncthreads();
  float* vp = vecg + (size_t)b*TRI;
  for (int e=tid; e<4096; e+=512){
    int i = e>>6, j = e&63;
    if (j >= i){
      int t0 = (i*(129 - i)) >> 1;
      vp[t0 + j - i] = Af[i][j];
    }
  }
}

// ---------------- kernel 3: FC + sigmoid ----------------
__global__ __launch_bounds__(512) void k_fc(const float* __restrict__ vecg,
    const float* __restrict__ fcw, const float* __restrict__ fcb,
    float* __restrict__ gate){
  __shared__ float fwL[16][2080];
  __shared__ __align__(16) float vecL[2080];
  int bg = blockIdx.x >> 4, pg = blockIdx.x & 15;
  int tid = threadIdx.x;
  for (int i=tid; i<8320; i+=512){
    int row = i/520, c4 = i - row*520;
    *(float4*)&fwL[row][c4<<2] = *(const float4*)(fcw + (size_t)(pg*16+row)*TRI + (c4<<2));
  }
  int p = tid >> 5, s = tid & 31;
  int base = s*65;
  float bias = fcb[pg*16 + p];
  for (int bi=0; bi<16; ++bi){
    int b = bg*16 + bi;
    __syncthreads();
    for (int i=tid; i<520; i+=512)
      *(float4*)&vecL[i<<2] = *(const float4*)(vecg + (size_t)b*TRI + (i<<2));
    __syncthreads();
    float acc = 0.f;
#pragma unroll 13
    for (int m=0; m<65; ++m)
      acc = fmaf(fwL[p][base+m], vecL[base+m], acc);
    acc += __shfl_down(acc, 16, 32);
    acc += __shfl_down(acc, 8, 32);
    acc += __shfl_down(acc, 4, 32);
    acc += __shfl_down(acc, 2, 32);
    acc += __shfl_down(acc, 1, 32);
    if (s==0)
      gate[(size_t)b*PLANES + pg*16 + p] = 1.f/(1.f + expf(-(acc + bias)));
  }
}

// ---------------- kernel 4: out = x * gate[b,c] ----------------
__global__ __launch_bounds__(256) void k_gate_mul(const float* __restrict__ x,
    const float* __restrict__ gate, float* __restrict__ out){
  size_t base = (size_t)blockIdx.x*256 + threadIdx.x;
#pragma unroll
  for (int k=0;k<8;k++){
    size_t i4 = base + (size_t)k*1048576;
    size_t e  = i4 << 2;
    int bc = (int)(e >> 10);
    float g = gate[bc];
    float4 v = *(const float4*)(x + e);
    v.x *= g; v.y *= g; v.z *= g; v.w *= g;
    *(float4*)(out + e) = v;
  }
}

extern "C" void kernel_launch(void* const* d_in, const int* in_sizes, int n_in,
                              void* d_out, int out_size, void* d_ws, size_t ws_size,
                              hipStream_t stream) {
  const float* x    = (const float*)d_in[0];
  const float* cw   = (const float*)d_in[1];
  const float* gam  = (const float*)d_in[2];
  const float* bet  = (const float*)d_in[3];
  const float* mu   = (const float*)d_in[4];
  const float* var  = (const float*)d_in[5];
  const float* fcw  = (const float*)d_in[6];
  const float* fcb  = (const float*)d_in[7];
  float* out = (float*)d_out;
  float* ws  = (float*)d_ws;

  unsigned int* whi = (unsigned int*)(ws + WHI_OFF);
  unsigned int* wlo = (unsigned int*)(ws + WLO_OFF);
  float* gate  = ws + GATE_OFF;
  float* psum  = ws + PSUM_OFF;
  float* pgram = ws + PGRAM_OFF;
  float* vecg  = ws + VEC_OFF;

  k_pack_w2<<<32, 256, 0, stream>>>(cw, whi, wlo);
  k_conv_gram<<<BATCH*8, 512, 0, stream>>>(x, whi, wlo, gam, bet, mu, var, pgram, psum);
  k_ns<<<BATCH, 512, 0, stream>>>(pgram, psum, vecg);
  k_fc<<<128, 512, 0, stream>>>(vecg, fcw, fcb, gate);
  k_gate_mul<<<4096, 256, 0, stream>>>(x, gate, out);
}

// Round 21
// 132.110 us; speedup vs baseline: 6.5442x; 6.5442x over previous
//
#include <hip/hip_runtime.h>
#include <math.h>

#define BATCH  128
#define CIN    256
#define HWSZ   1024
#define NATT   64
#define TRI    2080
#define PLANES 256

typedef __attribute__((ext_vector_type(8))) short short8v;
typedef __attribute__((ext_vector_type(4))) float f32x4;

// raw barrier: LDS-visibility drain only, NO vmcnt drain (prefetch stays in flight)
#define BAR() { asm volatile("s_waitcnt lgkmcnt(0)" ::: "memory"); __builtin_amdgcn_s_barrier(); }

// ---------------- workspace layout (float slots) ----------------
static const size_t WHI_OFF   = 0;         // uint [64][128]       8192
static const size_t WLO_OFF   = 8192;      // uint [64][128]       8192
static const size_t GATE_OFF  = 16384;     // [128][256]           32768
static const size_t PSUM_OFF  = 49152;     // [1024][64]           65536
static const size_t PGRAM_OFF = 114688;    // [1024][64][64]       4194304
static const size_t VEC_OFF   = 4308992;   // [128][2080]          266240

// ---------------- helpers ----------------
__device__ __forceinline__ unsigned int bf16rne(float f){
  unsigned int u = __float_as_uint(f);
  return (u + 0x7fffu + ((u>>16)&1u)) >> 16;
}
__device__ __forceinline__ unsigned int pk2(float a, float b){
  return bf16rne(a) | (bf16rne(b)<<16);
}
__device__ __forceinline__ unsigned int pack_hl(float v){
  unsigned int b  = __float_as_uint(v);
  unsigned int hb = b >> 16;
  float hif = __uint_as_float(hb << 16);
  float lo  = v - hif;
  unsigned int lb = __float_as_uint(lo) >> 16;
  return hb | (lb << 16);
}
union U4S8 { uint4 u; short8v s; };
__device__ __forceinline__ short8v bc8(uint4 v){ U4S8 x; x.u = v; return x.s; }

__device__ __forceinline__ void unpack8p(const unsigned int* w, short8v& h, short8v& l){
  union { unsigned int u[4]; short8v s; } H, L;
#pragma unroll
  for (int i=0;i<4;i++){
    H.u[i] = __builtin_amdgcn_perm(w[2*i+1], w[2*i], 0x05040100u);
    L.u[i] = __builtin_amdgcn_perm(w[2*i+1], w[2*i], 0x07060302u);
  }
  h = H.s; l = L.s;
}
__device__ __forceinline__ void unpack8v(uint4 a, uint4 b, short8v& h, short8v& l){
  unsigned int w[8] = {a.x,a.y,a.z,a.w,b.x,b.y,b.z,b.w};
  unpack8p(w, h, l);
}

// ---------------- kernel 0: pack conv_w to bf16 hi/lo PAIR arrays ----------------
__global__ void k_pack_w2(const float* __restrict__ w,
                          unsigned int* __restrict__ whi, unsigned int* __restrict__ wlo){
  int idx = blockIdx.x*256 + threadIdx.x;
  if (idx < 64*128){
    float w0 = w[2*idx], w1 = w[2*idx+1];
    unsigned int h0 = __float_as_uint(w0)>>16, h1 = __float_as_uint(w1)>>16;
    float l0f = w0 - __uint_as_float(h0<<16);
    float l1f = w1 - __uint_as_float(h1<<16);
    whi[idx] = h0 | (h1<<16);
    wlo[idx] = (__float_as_uint(l0f)>>16) | ((__float_as_uint(l1f)>>16)<<16);
  }
}

// ---------------- kernel 1: fused conv+BN+ReLU+gram — FLOAT4 x-loads ----------
// R16 structure, ONE isolated change: staging loads are per-lane float4
// (16B/lane; 512B/segment per row) instead of scalar dwords (R20 PMC showed
// scalar staging capped fetch at 2.0 TB/s = the whole kernel's limiter).
// LDS layout flipped to cp-major [16][132]: pack-writes are contiguous b128
// (conflict-free), B-frag reads are 4x b32 at 2 lanes/bank (free).
__global__ __launch_bounds__(512, 6) void k_conv_gram(
    const float* __restrict__ x,
    const unsigned int* __restrict__ whi, const unsigned int* __restrict__ wlo,
    const float* __restrict__ gam, const float* __restrict__ bet,
    const float* __restrict__ mu,  const float* __restrict__ var,
    float* __restrict__ pgram, float* __restrict__ psum){
  __shared__ __align__(16) unsigned char pool[17408];   // yt 64x68x4 = 17408
  __shared__ float scl[64], shf[64];
  __shared__ float psl[2][64];
  unsigned int (*xsb[2])[132];                          // 2 x 16x132x4 = 16896
  xsb[0] = (unsigned int (*)[132])pool;
  xsb[1] = xsb[0] + 16;
  unsigned int (*yt)[68]  = (unsigned int (*)[68])pool; // alias
  // XCD swizzle: all 8 chunks of batch b on one XCD
  int i_hw  = blockIdx.x;
  int xcd   = i_hw & 7;
  int slot  = i_hw >> 3;
  int b     = xcd + ((slot >> 3) << 3);
  int chunk = slot & 7;
  int pslot = b*8 + chunk;
  int tid = threadIdx.x;
  int l = tid & 63, w = tid >> 6;
  int i16 = l & 15, q = l >> 4;
  int o0 = (w & 3) * 16, phalf = (w >> 2) * 64;
  if (tid < 64){
    float sc = gam[tid]*rsqrtf(var[tid]+1e-5f);
    scl[tid] = sc; shf[tid] = bet[tid] - mu[tid]*sc;
  }
  int cS = tid >> 5;          // 0..15 : c-pair (row in xs)
  int pS = tid & 31;          // float4 index within the 128-px chunk
  const float* xc = x + ((size_t)b*CIN + 2*cS)*HWSZ + chunk*128 + 4*pS;
  const unsigned int* whiR = whi + (o0+i16)*128 + q*4;
  const unsigned int* wloR = wlo + (o0+i16)*128 + q*4;
  f32x4 acc[4];
#pragma unroll
  for (int t=0;t<4;t++) acc[t] = (f32x4){0.f,0.f,0.f,0.f};

  // x: 3 prefetch reg sets (distance 3, float4); w: 2 parity slots (distance 2)
  float4 va[3], vb[3];
  uint4 wh[2], wl[2];
#define LOADSET(R, S) { const float* xn = xc + (size_t)(S)*32*HWSZ; \
  va[R] = *(const float4*)xn; vb[R] = *(const float4*)(xn + HWSZ); }
#define WRITESET(R, BUF) { uint4 u_; \
  u_.x = pk2(va[R].x, vb[R].x); u_.y = pk2(va[R].y, vb[R].y); \
  u_.z = pk2(va[R].z, vb[R].z); u_.w = pk2(va[R].w, vb[R].w); \
  *(uint4*)&xsb[BUF][cS][4*pS] = u_; }
#define WLOAD(P, S) { wh[P] = *(const uint4*)(whiR + (S)*16); \
                      wl[P] = *(const uint4*)(wloR + (S)*16); }

  // prologue: x tiles 0,1,2 in regs; w steps 0,1 in slots; buf0 <- x0
  LOADSET(0, 0)
  LOADSET(1, 1)
  LOADSET(2, 2)
  WLOAD(0, 0)
  WLOAD(1, 1)
  WRITESET(0, 0)

#pragma unroll
  for (int cc=0; cc<8; ++cc){
    BAR();                                        // lgkm-only
    uint4 ahi = wh[cc & 1];                       // w(cc) — read BEFORE slot reuse
    uint4 alo = wl[cc & 1];
    if (cc < 5) LOADSET(cc % 3, cc + 3)           // x for step cc+3
    if (cc < 6) WLOAD(cc & 1, cc + 2)             // w for step cc+2 into freed slot
    unsigned int (*xsB)[132] = xsb[cc & 1];
    int q4 = q*4;
#pragma unroll
    for (int t=0;t<4;t++){
      int px = phalf + t*16 + i16;
      uint4 bv;
      bv.x = xsB[q4+0][px];
      bv.y = xsB[q4+1][px];
      bv.z = xsB[q4+2][px];
      bv.w = xsB[q4+3][px];
      acc[t] = __builtin_amdgcn_mfma_f32_16x16x32_bf16(bc8(ahi), bc8(bv), acc[t],0,0,0);
      acc[t] = __builtin_amdgcn_mfma_f32_16x16x32_bf16(bc8(alo), bc8(bv), acc[t],0,0,0);
    }
    if (cc < 7) WRITESET((cc + 1) % 3, (cc + 1) & 1)   // x(cc+1) -> other buf
  }
#undef LOADSET
#undef WRITESET
#undef WLOAD
  __syncthreads();   // xs dead; pool becomes yt
  // epilogue: BN + ReLU, pack pairs -> yt; row sums via 16-lane shuffles
  float rs[4] = {0.f,0.f,0.f,0.f};
#pragma unroll
  for (int t=0;t<4;t++){
    int p = phalf + t*16 + i16;
#pragma unroll
    for (int r=0;r<4;r++){
      int o = o0 + q*4 + r;
      float vv = fmaf(acc[t][r], scl[o], shf[o]);
      vv = vv>0.f ? vv : 0.f;
      rs[r] += vv;
      float nb = __shfl_xor(vv, 1);
      if (!(i16 & 1)) yt[o][p>>1] = pk2(vv, nb);
    }
  }
#pragma unroll
  for (int r=0;r<4;r++){
#pragma unroll
    for (int m=1;m<16;m<<=1) rs[r] += __shfl_xor(rs[r], m, 16);
  }
  if (i16 == 0){
#pragma unroll
    for (int r=0;r<4;r++) psl[w>>2][o0 + q*4 + r] = rs[r];
  }
  __syncthreads();
  if (tid < 64) psum[(size_t)pslot*64 + tid] = psl[0][tid] + psl[1][tid];
  // gram = Y Y^T over 128 px: wave -> tiles (ti,tj0),(ti,tj0+1)
  {
    f32x4 g0 = (f32x4){0.f,0.f,0.f,0.f}, g1 = g0;
    int ti = w >> 1, tj0 = (w & 1) * 2;
#pragma unroll
    for (int ks=0; ks<4; ks++){
      int ku = ks*16 + q*4;
      uint4 a  = *(const uint4*)&yt[ti*16      + i16][ku];
      uint4 b0 = *(const uint4*)&yt[tj0*16     + i16][ku];
      uint4 b1 = *(const uint4*)&yt[(tj0+1)*16 + i16][ku];
      g0 = __builtin_amdgcn_mfma_f32_16x16x32_bf16(bc8(a), bc8(b0), g0,0,0,0);
      g1 = __builtin_amdgcn_mfma_f32_16x16x32_bf16(bc8(a), bc8(b1), g1,0,0,0);
    }
    float* pg = pgram + (size_t)pslot*4096;
#pragma unroll
    for (int r=0;r<4;r++){
      int i = ti*16 + q*4 + r;
      pg[i*64 + tj0*16     + i16] = g0[r];
      pg[i*64 + (tj0+1)*16 + i16] = g1[r];
    }
  }
}

// P = L @ R for 64x64 packed hi/lo (R symmetric: B-frags read row-wise).
__device__ __forceinline__ void wave_mm(const unsigned int (*PL)[68],
                                        const unsigned int (*PR)[68],
                                        int lane, int rp, int ch, f32x4* acc){
  f32x4 z = {0.f,0.f,0.f,0.f};
  acc[0] = z; acc[1] = z;
  int i15 = lane & 15, q = lane >> 4;
  int row = rp*16 + i15;
#pragma unroll
  for (int s=0; s<2; s++){
    int kbase = s*32 + (q<<3);
    uint4 a0 = *(const uint4*)&PL[row][kbase];
    uint4 a1 = *(const uint4*)&PL[row][kbase+4];
    short8v ah, al; unpack8v(a0,a1,ah,al);
#pragma unroll
    for (int ct=0; ct<2; ct++){
      const unsigned int* bp = &PR[ch*32 + ct*16 + i15][kbase];
      uint4 b0 = *(const uint4*)bp;
      uint4 b1 = *(const uint4*)(bp+4);
      short8v bh, bl; unpack8v(b0,b1,bh,bl);
      acc[ct] = __builtin_amdgcn_mfma_f32_16x16x32_bf16(ah, bh, acc[ct], 0,0,0);
      acc[ct] = __builtin_amdgcn_mfma_f32_16x16x32_bf16(ah, bl, acc[ct], 0,0,0);
      acc[ct] = __builtin_amdgcn_mfma_f32_16x16x32_bf16(al, bh, acc[ct], 0,0,0);
    }
  }
}

template<int MODE>  // 0: pack(v)  1: pack(0.5*(3I-v))  2: pack(3I-v)
__device__ __forceinline__ void store_packed(unsigned int (*PD)[68], const f32x4* acc,
                                             int lane, int rp, int ch){
  int i15 = lane & 15, q = lane >> 4;
#pragma unroll
  for (int ct=0; ct<2; ct++){
    int col = ch*32 + ct*16 + i15;
#pragma unroll
    for (int r=0; r<4; r++){
      int row = rp*16 + q*4 + r;
      float v = acc[ct][r];
      if (MODE==1) v = 0.5f*((row==col?3.f:0.f) - v);
      if (MODE==2) v = (row==col?3.f:0.f) - v;
      PD[row][col] = pack_hl(v);
    }
  }
}

// ---------------- kernel 2: Newton-Schulz + triuvec -> vec ----------------
__global__ __launch_bounds__(512) void k_ns(const float* __restrict__ pgram,
    const float* __restrict__ psum, float* __restrict__ vecg){
  __shared__ float Af[64][68];
  __shared__ unsigned int PA[64][68];
  __shared__ unsigned int PT[64][68];
  __shared__ unsigned int PY[64][68];
  __shared__ unsigned int PZ[64][68];
  __shared__ float meanl[64];
  __shared__ float snorm;
  int b = blockIdx.x, tid = threadIdx.x;
  int lane = tid & 63, wv = tid >> 6, rp = wv & 3, ch = wv >> 2;
  const float* pc0 = pgram + ((size_t)b*8) * (NATT*NATT);
  if (tid < 64){
    const float* ps = psum + (size_t)b*512;
    float s = 0.f;
#pragma unroll
    for (int k=0;k<8;k++) s += ps[64*k + tid];
    meanl[tid] = s * (1.f/1024.f);
  }
  __syncthreads();
  for (int e=tid; e<4096; e+=512){
    int i = e>>6, j = e&63;
    float s = 0.f;
#pragma unroll
    for (int k=0;k<8;k++) s += pc0[4096*k + e];
    Af[i][j] = s * (1.f/1024.f) - meanl[i]*meanl[j];
  }
  __syncthreads();
  if (tid < 64){
    float s = Af[tid][tid];
#pragma unroll
    for (int off=32; off; off>>=1) s += __shfl_down(s, off);
    if (tid==0) snorm = s;
  }
  __syncthreads();
  float normA = snorm;
  float inv = 1.f/normA;
  for (int e=tid; e<4096; e+=512){
    int i = e>>6, j = e&63;
    float an = Af[i][j]*inv;
    float t  = 0.5f*((i==j?3.f:0.f) - an);
    unsigned int pt = pack_hl(t);
    PA[i][j] = pack_hl(an);
    PT[i][j] = pt;
    PZ[i][j] = pt;
  }
  __syncthreads();

  f32x4 accY[2], accZ[2];
  wave_mm(PA, PT, lane, rp, ch, accY);
  store_packed<0>(PY, accY, lane, rp, ch);
  __syncthreads();

  for (int it=0; it<3; ++it){
    wave_mm(PZ, PY, lane, rp, ch, accY);
    store_packed<1>(PT, accY, lane, rp, ch);
    __syncthreads();
    wave_mm(PY, PT, lane, rp, ch, accY);
    wave_mm(PT, PZ, lane, rp, ch, accZ);
    __syncthreads();
    store_packed<0>(PY, accY, lane, rp, ch);
    store_packed<0>(PZ, accZ, lane, rp, ch);
    __syncthreads();
  }
  wave_mm(PZ, PY, lane, rp, ch, accY);
  store_packed<2>(PT, accY, lane, rp, ch);
  __syncthreads();
  wave_mm(PY, PT, lane, rp, ch, accY);
  float scl = 0.5f * sqrtf(normA);
  {
    int i15 = lane & 15, q = lane >> 4;
#pragma unroll
    for (int ct=0; ct<2; ct++){
      int col = ch*32 + ct*16 + i15;
#pragma unroll
      for (int r=0; r<4; r++){
        int row = rp*16 + q*4 + r;
        Af[row][col] = accY[ct][r]*scl;
      }
    }
  }
  __syncthreads();
  float* vp = vecg + (size_t)b*TRI;
  for (int e=tid; e<4096; e+=512){
    int i = e>>6, j = e&63;
    if (j >= i){
      int t0 = (i*(129 - i)) >> 1;
      vp[t0 + j - i] = Af[i][j];
    }
  }
}

// ---------------- kernel 3: FC + sigmoid ----------------
__global__ __launch_bounds__(512) void k_fc(const float* __restrict__ vecg,
    const float* __restrict__ fcw, const float* __restrict__ fcb,
    float* __restrict__ gate){
  __shared__ float fwL[16][2080];
  __shared__ __align__(16) float vecL[2080];
  int bg = blockIdx.x >> 4, pg = blockIdx.x & 15;
  int tid = threadIdx.x;
  for (int i=tid; i<8320; i+=512){
    int row = i/520, c4 = i - row*520;
    *(float4*)&fwL[row][c4<<2] = *(const float4*)(fcw + (size_t)(pg*16+row)*TRI + (c4<<2));
  }
  int p = tid >> 5, s = tid & 31;
  int base = s*65;
  float bias = fcb[pg*16 + p];
  for (int bi=0; bi<16; ++bi){
    int b = bg*16 + bi;
    __syncthreads();
    for (int i=tid; i<520; i+=512)
      *(float4*)&vecL[i<<2] = *(const float4*)(vecg + (size_t)b*TRI + (i<<2));
    __syncthreads();
    float acc = 0.f;
#pragma unroll 13
    for (int m=0; m<65; ++m)
      acc = fmaf(fwL[p][base+m], vecL[base+m], acc);
    acc += __shfl_down(acc, 16, 32);
    acc += __shfl_down(acc, 8, 32);
    acc += __shfl_down(acc, 4, 32);
    acc += __shfl_down(acc, 2, 32);
    acc += __shfl_down(acc, 1, 32);
    if (s==0)
      gate[(size_t)b*PLANES + pg*16 + p] = 1.f/(1.f + expf(-(acc + bias)));
  }
}

// ---------------- kernel 4: out = x * gate[b,c] ----------------
__global__ __launch_bounds__(256) void k_gate_mul(const float* __restrict__ x,
    const float* __restrict__ gate, float* __restrict__ out){
  size_t base = (size_t)blockIdx.x*256 + threadIdx.x;
#pragma unroll
  for (int k=0;k<8;k++){
    size_t i4 = base + (size_t)k*1048576;
    size_t e  = i4 << 2;
    int bc = (int)(e >> 10);
    float g = gate[bc];
    float4 v = *(const float4*)(x + e);
    v.x *= g; v.y *= g; v.z *= g; v.w *= g;
    *(float4*)(out + e) = v;
  }
}

extern "C" void kernel_launch(void* const* d_in, const int* in_sizes, int n_in,
                              void* d_out, int out_size, void* d_ws, size_t ws_size,
                              hipStream_t stream) {
  const float* x    = (const float*)d_in[0];
  const float* cw   = (const float*)d_in[1];
  const float* gam  = (const float*)d_in[2];
  const float* bet  = (const float*)d_in[3];
  const float* mu   = (const float*)d_in[4];
  const float* var  = (const float*)d_in[5];
  const float* fcw  = (const float*)d_in[6];
  const float* fcb  = (const float*)d_in[7];
  float* out = (float*)d_out;
  float* ws  = (float*)d_ws;

  unsigned int* whi = (unsigned int*)(ws + WHI_OFF);
  unsigned int* wlo = (unsigned int*)(ws + WLO_OFF);
  float* gate  = ws + GATE_OFF;
  float* psum  = ws + PSUM_OFF;
  float* pgram = ws + PGRAM_OFF;
  float* vecg  = ws + VEC_OFF;

  k_pack_w2<<<32, 256, 0, stream>>>(cw, whi, wlo);
  k_conv_gram<<<BATCH*8, 512, 0, stream>>>(x, whi, wlo, gam, bet, mu, var, pgram, psum);
  k_ns<<<BATCH, 512, 0, stream>>>(pgram, psum, vecg);
  k_fc<<<128, 512, 0, stream>>>(vecg, fcw, fcb, gate);
  k_gate_mul<<<4096, 256, 0, stream>>>(x, gate, out);
}

// Round 22
// 129.750 us; speedup vs baseline: 6.6632x; 1.0182x over previous
//
#include <hip/hip_runtime.h>
#include <math.h>

#define BATCH  128
#define CIN    256
#define HWSZ   1024
#define NATT   64
#define TRI    2080
#define PLANES 256

typedef __attribute__((ext_vector_type(8))) short short8v;
typedef __attribute__((ext_vector_type(4))) float f32x4;

// raw barrier: LDS-visibility drain only, NO vmcnt drain (prefetch stays in flight)
#define BAR() { asm volatile("s_waitcnt lgkmcnt(0)" ::: "memory"); __builtin_amdgcn_s_barrier(); }

// ---------------- workspace layout (float slots) ----------------
static const size_t WHI_OFF   = 0;         // uint [64][128]       8192
static const size_t WLO_OFF   = 8192;      // uint [64][128]       8192
static const size_t GATE_OFF  = 16384;     // [128][256]           32768
static const size_t PSUM_OFF  = 49152;     // [512][64]            32768
static const size_t PGRAM_OFF = 81920;     // [512][64][64]        2097152
static const size_t VEC_OFF   = 2179072;   // [128][2080]          266240

// ---------------- helpers ----------------
__device__ __forceinline__ unsigned int bf16rne(float f){
  unsigned int u = __float_as_uint(f);
  return (u + 0x7fffu + ((u>>16)&1u)) >> 16;
}
__device__ __forceinline__ unsigned int pk2(float a, float b){
  return bf16rne(a) | (bf16rne(b)<<16);
}
__device__ __forceinline__ unsigned int pack_hl(float v){
  unsigned int b  = __float_as_uint(v);
  unsigned int hb = b >> 16;
  float hif = __uint_as_float(hb << 16);
  float lo  = v - hif;
  unsigned int lb = __float_as_uint(lo) >> 16;
  return hb | (lb << 16);
}
union U4S8 { uint4 u; short8v s; };
__device__ __forceinline__ short8v bc8(uint4 v){ U4S8 x; x.u = v; return x.s; }

__device__ __forceinline__ void unpack8p(const unsigned int* w, short8v& h, short8v& l){
  union { unsigned int u[4]; short8v s; } H, L;
#pragma unroll
  for (int i=0;i<4;i++){
    H.u[i] = __builtin_amdgcn_perm(w[2*i+1], w[2*i], 0x05040100u);
    L.u[i] = __builtin_amdgcn_perm(w[2*i+1], w[2*i], 0x07060302u);
  }
  h = H.s; l = L.s;
}
__device__ __forceinline__ void unpack8v(uint4 a, uint4 b, short8v& h, short8v& l){
  unsigned int w[8] = {a.x,a.y,a.z,a.w,b.x,b.y,b.z,b.w};
  unpack8p(w, h, l);
}

// ---------------- kernel 0: pack conv_w to bf16 hi/lo PAIR arrays ----------------
__global__ void k_pack_w2(const float* __restrict__ w,
                          unsigned int* __restrict__ whi, unsigned int* __restrict__ wlo){
  int idx = blockIdx.x*256 + threadIdx.x;
  if (idx < 64*128){
    float w0 = w[2*idx], w1 = w[2*idx+1];
    unsigned int h0 = __float_as_uint(w0)>>16, h1 = __float_as_uint(w1)>>16;
    float l0f = w0 - __uint_as_float(h0<<16);
    float l1f = w1 - __uint_as_float(h1<<16);
    whi[idx] = h0 | (h1<<16);
    wlo[idx] = (__float_as_uint(l0f)>>16) | ((__float_as_uint(l1f)>>16)<<16);
  }
}

// ---------------- kernel 1: fused conv+BN+ReLU+gram — 256-px chunks -----------
// CONTIGUITY EXPERIMENT: px-chunk 128 -> 256 so each c-row read is 1 KB
// contiguous (R21: 512B; R17: 256B regressed; gate_mul sequential = 6.3 TB/s).
// grid: 128 b x 4 quarters = 512 blocks, 512 threads (8 waves).
// wave = (o-panel w&3) x (px-half w>>2, 128 px) -> 8 tiles, 32 acc VGPR.
// Pipeline: x dist-3 reg sets (4x float4/lane), w dist-2 parity slots,
// slot-read-before-reuse, LDS dbuf, raw lgkm-only barriers, XCD swizzle.
__global__ __launch_bounds__(512, 4) void k_conv_gram(
    const float* __restrict__ x,
    const unsigned int* __restrict__ whi, const unsigned int* __restrict__ wlo,
    const float* __restrict__ gam, const float* __restrict__ bet,
    const float* __restrict__ mu,  const float* __restrict__ var,
    float* __restrict__ pgram, float* __restrict__ psum){
  __shared__ __align__(16) unsigned char pool[2*16*268*4];   // 34304 B
  __shared__ float scl[64], shf[64];
  __shared__ float psl[2][64];
  unsigned int (*xsb[2])[268];
  xsb[0] = (unsigned int (*)[268])pool;
  xsb[1] = xsb[0] + 16;
  unsigned int (*yt)[132] = (unsigned int (*)[132])pool;     // alias: 33792 B
  // XCD swizzle: all 4 quarter-blocks of batch b on one XCD
  int i_hw  = blockIdx.x;
  int xcd   = i_hw & 7;
  int slot  = i_hw >> 3;
  int b     = xcd + ((slot >> 2) << 3);
  int quarter = slot & 3;
  int pslot = b*4 + quarter;
  int tid = threadIdx.x;
  int l = tid & 63, w = tid >> 6;
  int i16 = l & 15, q = l >> 4;
  int o0 = (w & 3) * 16, ph = (w >> 2);            // px-half: ph*128
  if (tid < 64){
    float sc = gam[tid]*rsqrtf(var[tid]+1e-5f);
    scl[tid] = sc; shf[tid] = bet[tid] - mu[tid]*sc;
  }
  int cS = tid >> 5;          // 0..15 : c-pair row
  int pS = tid & 31;          // float4 col (first of two: pS, pS+32)
  const float* xc = x + ((size_t)b*CIN + 2*cS)*HWSZ + quarter*256 + 4*pS;
  const unsigned int* whiR = whi + (o0+i16)*128 + q*4;
  const unsigned int* wloR = wlo + (o0+i16)*128 + q*4;
  f32x4 acc[8];
#pragma unroll
  for (int t=0;t<8;t++) acc[t] = (f32x4){0.f,0.f,0.f,0.f};

  // x: 3 prefetch reg sets (distance 3, 4x float4); w: 2 parity slots (distance 2)
  float4 va[3][2], vb[3][2];
  uint4 wh[2], wl[2];
#define LOADSET(R, S) { const float* xn = xc + (size_t)(S)*32*HWSZ; \
  va[R][0] = *(const float4*)xn;         vb[R][0] = *(const float4*)(xn + HWSZ); \
  va[R][1] = *(const float4*)(xn + 128); vb[R][1] = *(const float4*)(xn + HWSZ + 128); }
#define WRITESET(R, BUF) { uint4 u0_, u1_; \
  u0_.x = pk2(va[R][0].x, vb[R][0].x); u0_.y = pk2(va[R][0].y, vb[R][0].y); \
  u0_.z = pk2(va[R][0].z, vb[R][0].z); u0_.w = pk2(va[R][0].w, vb[R][0].w); \
  u1_.x = pk2(va[R][1].x, vb[R][1].x); u1_.y = pk2(va[R][1].y, vb[R][1].y); \
  u1_.z = pk2(va[R][1].z, vb[R][1].z); u1_.w = pk2(va[R][1].w, vb[R][1].w); \
  *(uint4*)&xsb[BUF][cS][4*pS] = u0_; \
  *(uint4*)&xsb[BUF][cS][4*pS + 128] = u1_; }
#define WLOAD(P, S) { wh[P] = *(const uint4*)(whiR + (S)*16); \
                      wl[P] = *(const uint4*)(wloR + (S)*16); }

  // prologue: x tiles 0,1,2 in regs; w steps 0,1 in slots; buf0 <- x0
  LOADSET(0, 0)
  LOADSET(1, 1)
  LOADSET(2, 2)
  WLOAD(0, 0)
  WLOAD(1, 1)
  WRITESET(0, 0)

#pragma unroll
  for (int cc=0; cc<8; ++cc){
    BAR();                                        // lgkm-only
    uint4 ahi = wh[cc & 1];                       // w(cc) — read BEFORE slot reuse
    uint4 alo = wl[cc & 1];
    if (cc < 5) LOADSET(cc % 3, cc + 3)           // x for step cc+3
    if (cc < 6) WLOAD(cc & 1, cc + 2)             // w for step cc+2 into freed slot
    unsigned int (*xsB)[268] = xsb[cc & 1];
    int q4 = q*4;
#pragma unroll
    for (int t=0;t<8;t++){
      int px = ph*128 + t*16 + i16;
      uint4 bv;
      bv.x = xsB[q4+0][px];
      bv.y = xsB[q4+1][px];
      bv.z = xsB[q4+2][px];
      bv.w = xsB[q4+3][px];
      acc[t] = __builtin_amdgcn_mfma_f32_16x16x32_bf16(bc8(ahi), bc8(bv), acc[t],0,0,0);
      acc[t] = __builtin_amdgcn_mfma_f32_16x16x32_bf16(bc8(alo), bc8(bv), acc[t],0,0,0);
    }
    if (cc < 7) WRITESET((cc + 1) % 3, (cc + 1) & 1)   // x(cc+1) -> other buf
  }
#undef LOADSET
#undef WRITESET
#undef WLOAD
  __syncthreads();   // xs dead; pool becomes yt
  // epilogue: BN + ReLU, pack px-pairs -> yt; row sums via 16-lane shuffles
  float rs[4] = {0.f,0.f,0.f,0.f};
#pragma unroll
  for (int t=0;t<8;t++){
    int px = ph*128 + t*16 + i16;
#pragma unroll
    for (int r=0;r<4;r++){
      int o = o0 + q*4 + r;
      float vv = fmaf(acc[t][r], scl[o], shf[o]);
      vv = vv>0.f ? vv : 0.f;
      rs[r] += vv;
      float nb = __shfl_xor(vv, 1);
      if (!(i16 & 1)) yt[o][px>>1] = pk2(vv, nb);
    }
  }
#pragma unroll
  for (int r=0;r<4;r++){
#pragma unroll
    for (int m=1;m<16;m<<=1) rs[r] += __shfl_xor(rs[r], m, 16);
  }
  if (i16 == 0){
#pragma unroll
    for (int r=0;r<4;r++) psl[w>>2][o0 + q*4 + r] = rs[r];
  }
  __syncthreads();
  if (tid < 64) psum[(size_t)pslot*64 + tid] = psl[0][tid] + psl[1][tid];
  // gram = Y Y^T over 256 px: wave -> tiles (ti,tj0),(ti,tj0+1)
  {
    f32x4 g0 = (f32x4){0.f,0.f,0.f,0.f}, g1 = g0;
    int ti = w >> 1, tj0 = (w & 1) * 2;
#pragma unroll
    for (int ks=0; ks<8; ks++){
      int ku = ks*16 + q*4;
      uint4 a  = *(const uint4*)&yt[ti*16      + i16][ku];
      uint4 b0 = *(const uint4*)&yt[tj0*16     + i16][ku];
      uint4 b1 = *(const uint4*)&yt[(tj0+1)*16 + i16][ku];
      g0 = __builtin_amdgcn_mfma_f32_16x16x32_bf16(bc8(a), bc8(b0), g0,0,0,0);
      g1 = __builtin_amdgcn_mfma_f32_16x16x32_bf16(bc8(a), bc8(b1), g1,0,0,0);
    }
    float* pg = pgram + (size_t)pslot*4096;
#pragma unroll
    for (int r=0;r<4;r++){
      int i = ti*16 + q*4 + r;
      pg[i*64 + tj0*16     + i16] = g0[r];
      pg[i*64 + (tj0+1)*16 + i16] = g1[r];
    }
  }
}

// P = L @ R for 64x64 packed hi/lo (R symmetric: B-frags read row-wise).
__device__ __forceinline__ void wave_mm(const unsigned int (*PL)[68],
                                        const unsigned int (*PR)[68],
                                        int lane, int rp, int ch, f32x4* acc){
  f32x4 z = {0.f,0.f,0.f,0.f};
  acc[0] = z; acc[1] = z;
  int i15 = lane & 15, q = lane >> 4;
  int row = rp*16 + i15;
#pragma unroll
  for (int s=0; s<2; s++){
    int kbase = s*32 + (q<<3);
    uint4 a0 = *(const uint4*)&PL[row][kbase];
    uint4 a1 = *(const uint4*)&PL[row][kbase+4];
    short8v ah, al; unpack8v(a0,a1,ah,al);
#pragma unroll
    for (int ct=0; ct<2; ct++){
      const unsigned int* bp = &PR[ch*32 + ct*16 + i15][kbase];
      uint4 b0 = *(const uint4*)bp;
      uint4 b1 = *(const uint4*)(bp+4);
      short8v bh, bl; unpack8v(b0,b1,bh,bl);
      acc[ct] = __builtin_amdgcn_mfma_f32_16x16x32_bf16(ah, bh, acc[ct], 0,0,0);
      acc[ct] = __builtin_amdgcn_mfma_f32_16x16x32_bf16(ah, bl, acc[ct], 0,0,0);
      acc[ct] = __builtin_amdgcn_mfma_f32_16x16x32_bf16(al, bh, acc[ct], 0,0,0);
    }
  }
}

template<int MODE>  // 0: pack(v)  1: pack(0.5*(3I-v))  2: pack(3I-v)
__device__ __forceinline__ void store_packed(unsigned int (*PD)[68], const f32x4* acc,
                                             int lane, int rp, int ch){
  int i15 = lane & 15, q = lane >> 4;
#pragma unroll
  for (int ct=0; ct<2; ct++){
    int col = ch*32 + ct*16 + i15;
#pragma unroll
    for (int r=0; r<4; r++){
      int row = rp*16 + q*4 + r;
      float v = acc[ct][r];
      if (MODE==1) v = 0.5f*((row==col?3.f:0.f) - v);
      if (MODE==2) v = (row==col?3.f:0.f) - v;
      PD[row][col] = pack_hl(v);
    }
  }
}

// ---------------- kernel 2: Newton-Schulz + triuvec -> vec ----------------
__global__ __launch_bounds__(512) void k_ns(const float* __restrict__ pgram,
    const float* __restrict__ psum, float* __restrict__ vecg){
  __shared__ float Af[64][68];
  __shared__ unsigned int PA[64][68];
  __shared__ unsigned int PT[64][68];
  __shared__ unsigned int PY[64][68];
  __shared__ unsigned int PZ[64][68];
  __shared__ float meanl[64];
  __shared__ float snorm;
  int b = blockIdx.x, tid = threadIdx.x;
  int lane = tid & 63, wv = tid >> 6, rp = wv & 3, ch = wv >> 2;
  const float* pc0 = pgram + ((size_t)b*4) * (NATT*NATT);
  if (tid < 64){
    const float* ps = psum + (size_t)b*256;
    float s = 0.f;
#pragma unroll
    for (int k=0;k<4;k++) s += ps[64*k + tid];
    meanl[tid] = s * (1.f/1024.f);
  }
  __syncthreads();
  for (int e=tid; e<4096; e+=512){
    int i = e>>6, j = e&63;
    float s = 0.f;
#pragma unroll
    for (int k=0;k<4;k++) s += pc0[4096*k + e];
    Af[i][j] = s * (1.f/1024.f) - meanl[i]*meanl[j];
  }
  __syncthreads();
  if (tid < 64){
    float s = Af[tid][tid];
#pragma unroll
    for (int off=32; off; off>>=1) s += __shfl_down(s, off);
    if (tid==0) snorm = s;
  }
  __syncthreads();
  float normA = snorm;
  float inv = 1.f/normA;
  for (int e=tid; e<4096; e+=512){
    int i = e>>6, j = e&63;
    float an = Af[i][j]*inv;
    float t  = 0.5f*((i==j?3.f:0.f) - an);
    unsigned int pt = pack_hl(t);
    PA[i][j] = pack_hl(an);
    PT[i][j] = pt;
    PZ[i][j] = pt;
  }
  __syncthreads();

  f32x4 accY[2], accZ[2];
  wave_mm(PA, PT, lane, rp, ch, accY);
  store_packed<0>(PY, accY, lane, rp, ch);
  __syncthreads();

  for (int it=0; it<3; ++it){
    wave_mm(PZ, PY, lane, rp, ch, accY);
    store_packed<1>(PT, accY, lane, rp, ch);
    __syncthreads();
    wave_mm(PY, PT, lane, rp, ch, accY);
    wave_mm(PT, PZ, lane, rp, ch, accZ);
    __syncthreads();
    store_packed<0>(PY, accY, lane, rp, ch);
    store_packed<0>(PZ, accZ, lane, rp, ch);
    __syncthreads();
  }
  wave_mm(PZ, PY, lane, rp, ch, accY);
  store_packed<2>(PT, accY, lane, rp, ch);
  __syncthreads();
  wave_mm(PY, PT, lane, rp, ch, accY);
  float scl = 0.5f * sqrtf(normA);
  {
    int i15 = lane & 15, q = lane >> 4;
#pragma unroll
    for (int ct=0; ct<2; ct++){
      int col = ch*32 + ct*16 + i15;
#pragma unroll
      for (int r=0; r<4; r++){
        int row = rp*16 + q*4 + r;
        Af[row][col] = accY[ct][r]*scl;
      }
    }
  }
  __syncthreads();
  float* vp = vecg + (size_t)b*TRI;
  for (int e=tid; e<4096; e+=512){
    int i = e>>6, j = e&63;
    if (j >= i){
      int t0 = (i*(129 - i)) >> 1;
      vp[t0 + j - i] = Af[i][j];
    }
  }
}

// ---------------- kernel 3: FC + sigmoid ----------------
__global__ __launch_bounds__(512) void k_fc(const float* __restrict__ vecg,
    const float* __restrict__ fcw, const float* __restrict__ fcb,
    float* __restrict__ gate){
  __shared__ float fwL[16][2080];
  __shared__ __align__(16) float vecL[2080];
  int bg = blockIdx.x >> 4, pg = blockIdx.x & 15;
  int tid = threadIdx.x;
  for (int i=tid; i<8320; i+=512){
    int row = i/520, c4 = i - row*520;
    *(float4*)&fwL[row][c4<<2] = *(const float4*)(fcw + (size_t)(pg*16+row)*TRI + (c4<<2));
  }
  int p = tid >> 5, s = tid & 31;
  int base = s*65;
  float bias = fcb[pg*16 + p];
  for (int bi=0; bi<16; ++bi){
    int b = bg*16 + bi;
    __syncthreads();
    for (int i=tid; i<520; i+=512)
      *(float4*)&vecL[i<<2] = *(const float4*)(vecg + (size_t)b*TRI + (i<<2));
    __syncthreads();
    float acc = 0.f;
#pragma unroll 13
    for (int m=0; m<65; ++m)
      acc = fmaf(fwL[p][base+m], vecL[base+m], acc);
    acc += __shfl_down(acc, 16, 32);
    acc += __shfl_down(acc, 8, 32);
    acc += __shfl_down(acc, 4, 32);
    acc += __shfl_down(acc, 2, 32);
    acc += __shfl_down(acc, 1, 32);
    if (s==0)
      gate[(size_t)b*PLANES + pg*16 + p] = 1.f/(1.f + expf(-(acc + bias)));
  }
}

// ---------------- kernel 4: out = x * gate[b,c] ----------------
__global__ __launch_bounds__(256) void k_gate_mul(const float* __restrict__ x,
    const float* __restrict__ gate, float* __restrict__ out){
  size_t base = (size_t)blockIdx.x*256 + threadIdx.x;
#pragma unroll
  for (int k=0;k<8;k++){
    size_t i4 = base + (size_t)k*1048576;
    size_t e  = i4 << 2;
    int bc = (int)(e >> 10);
    float g = gate[bc];
    float4 v = *(const float4*)(x + e);
    v.x *= g; v.y *= g; v.z *= g; v.w *= g;
    *(float4*)(out + e) = v;
  }
}

extern "C" void kernel_launch(void* const* d_in, const int* in_sizes, int n_in,
                              void* d_out, int out_size, void* d_ws, size_t ws_size,
                              hipStream_t stream) {
  const float* x    = (const float*)d_in[0];
  const float* cw   = (const float*)d_in[1];
  const float* gam  = (const float*)d_in[2];
  const float* bet  = (const float*)d_in[3];
  const float* mu   = (const float*)d_in[4];
  const float* var  = (const float*)d_in[5];
  const float* fcw  = (const float*)d_in[6];
  const float* fcb  = (const float*)d_in[7];
  float* out = (float*)d_out;
  float* ws  = (float*)d_ws;

  unsigned int* whi = (unsigned int*)(ws + WHI_OFF);
  unsigned int* wlo = (unsigned int*)(ws + WLO_OFF);
  float* gate  = ws + GATE_OFF;
  float* psum  = ws + PSUM_OFF;
  float* pgram = ws + PGRAM_OFF;
  float* vecg  = ws + VEC_OFF;

  k_pack_w2<<<32, 256, 0, stream>>>(cw, whi, wlo);
  k_conv_gram<<<BATCH*4, 512, 0, stream>>>(x, whi, wlo, gam, bet, mu, var, pgram, psum);
  k_ns<<<BATCH, 512, 0, stream>>>(pgram, psum, vecg);
  k_fc<<<128, 512, 0, stream>>>(vecg, fcw, fcb, gate);
  k_gate_mul<<<4096, 256, 0, stream>>>(x, gate, out);
}